// Round 1
// baseline (166.416 us; speedup 1.0000x reference)
//
#include <hip/hip_runtime.h>

#define BB 8
#define TT 2048
#define CC 1024
#define HH 64
#define MM (BB * TT)   // 16384 rows

typedef _Float16 half8 __attribute__((ext_vector_type(8)));
typedef _Float16 half4 __attribute__((ext_vector_type(4)));
typedef float floatx4 __attribute__((ext_vector_type(4)));

// 16-lane all-reduce max via DPP row-rotate butterfly (VALU pipe, no LDS).
template <int CTRL>
__device__ __forceinline__ float dpp_max_step(float x)
{
    union { float f; int i; } u, v;
    u.f = x;
    v.i = __builtin_amdgcn_update_dpp(u.i, u.i, CTRL, 0xf, 0xf, false);
    return fmaxf(x, v.f);
}
__device__ __forceinline__ float rowmax16(float x)
{
    x = dpp_max_step<0x128>(x);   // ROW_ROR:8
    x = dpp_max_step<0x124>(x);   // ROW_ROR:4
    x = dpp_max_step<0x122>(x);   // ROW_ROR:2
    x = dpp_max_step<0x121>(x);   // ROW_ROR:1
    return x;
}

// ---------------------------------------------------------------------------
// Kernel 0: pack W into chunk-major fp16 layout:
//   Wp[(c*192 + row)*32 + kk] = Wscaled[row][c*32 + kk]   (c = K-chunk of 32)
// rows 0..63 = Wq*8 (sqrt(H) fold), 64..127 = Wk, 128..191 = Wv.
// A 16x16x32 B-fragment (16 rows x k32) is contiguous 1 KB.
// ---------------------------------------------------------------------------
__global__ __launch_bounds__(256)
void w_pack(const float* __restrict__ Wk, const float* __restrict__ Wq,
            const float* __restrict__ Wv, _Float16* __restrict__ Wp)
{
    const int idx = (blockIdx.x * 256 + threadIdx.x) * 8;  // 0..196600
    const int c   = idx / 6144;          // 192*32 = 6144
    const int rm  = idx - c * 6144;
    const int row = rm >> 5;             // 0..191
    const int kk  = rm & 31;             // 0,8,16,24
    const int which = row >> 6;
    const float* __restrict__ src = (which == 0) ? Wq : ((which == 1) ? Wk : Wv);
    const float scale = (which == 0) ? 8.0f : 1.0f;
    const int srow = row & 63;
    const int k = c * 32 + kk;
    const float4 a = *reinterpret_cast<const float4*>(&src[srow * 1024 + k]);
    const float4 b = *reinterpret_cast<const float4*>(&src[srow * 1024 + k + 4]);
    const half8 o = { (_Float16)(a.x * scale), (_Float16)(a.y * scale),
                      (_Float16)(a.z * scale), (_Float16)(a.w * scale),
                      (_Float16)(b.x * scale), (_Float16)(b.y * scale),
                      (_Float16)(b.z * scale), (_Float16)(b.w * scale) };
    *reinterpret_cast<half8*>(&Wp[idx]) = o;
}

// ---------------------------------------------------------------------------
// Kernel 1: QKV projection, v8.
// Wave-tile 16 rows x 48 cols -> 4096 single-wave blocks = 16 waves/CU
// (4/SIMD, was 2/SIMD at 2048 blocks).  Depth-2 register software pipeline
// (two named buffer sets; compute chunk c, then issue loads for chunk c+2).
// Block-ID map: mtile = gw & 1023, nq = gw >> 10 -> the 4 waves sharing an
// x-row slab are 1024 apart in block ID == same XCD under i%8 round-robin,
// so the 4-way x re-read stays in that XCD's L2.
// Outputs identical to v7: q16 row-major; Kp/Vp MFMA-fragment-packed.
// ---------------------------------------------------------------------------
__global__ __launch_bounds__(64, 4)
void qkv8(const float* __restrict__ x, const _Float16* __restrict__ Wp,
          _Float16* __restrict__ q16, _Float16* __restrict__ Kp,
          _Float16* __restrict__ Vp)
{
    const int lane  = threadIdx.x;
    const int gw    = blockIdx.x;        // 0..4095
    const int mtile = gw & 1023;         // 0..1023
    const int nq    = gw >> 10;          // 0..3 : cols nq*48 .. +47
    const int m_base = mtile * 16;
    const int fm = lane & 15;
    const int fq = lane >> 4;
    const int fk = fq * 8;
    const int fr = fq * 4;

    const float*    __restrict__ xrow = &x[(size_t)(m_base + fm) * CC + fk];
    const _Float16* __restrict__ wb   = &Wp[(nq * 48 + fm) * 32 + fk];

    floatx4 acc[3];
    #pragma unroll
    for (int n = 0; n < 3; ++n)
        #pragma unroll
        for (int r = 0; r < 4; ++r) acc[n][r] = 0.0f;

    // depth-2 pipeline: buf0 holds even chunks, buf1 odd chunks.
    float4 xa0, xb0, xa1, xb1;
    half8 w0[3], w1[3];

    xa0 = *reinterpret_cast<const float4*>(xrow);
    xb0 = *reinterpret_cast<const float4*>(xrow + 4);
    xa1 = *reinterpret_cast<const float4*>(xrow + 32);
    xb1 = *reinterpret_cast<const float4*>(xrow + 36);
    #pragma unroll
    for (int n = 0; n < 3; ++n) {
        w0[n] = *reinterpret_cast<const half8*>(wb + n * 512);
        w1[n] = *reinterpret_cast<const half8*>(wb + 6144 + n * 512);
    }

    // main loop: chunks 0..29 computed here, loads issued up to chunk 31
    for (int cc = 0; cc < 15; ++cc) {
        const int c0 = cc * 2;
        {   // compute chunk c0 (buf0)
            const half8 af = { (_Float16)xa0.x, (_Float16)xa0.y, (_Float16)xa0.z, (_Float16)xa0.w,
                               (_Float16)xb0.x, (_Float16)xb0.y, (_Float16)xb0.z, (_Float16)xb0.w };
            #pragma unroll
            for (int n = 0; n < 3; ++n)
                acc[n] = __builtin_amdgcn_mfma_f32_16x16x32_f16(af, w0[n], acc[n], 0, 0, 0);
        }
        {   // issue loads for chunk c0+2 into buf0
            const float* xp = xrow + (c0 + 2) * 32;
            xa0 = *reinterpret_cast<const float4*>(xp);
            xb0 = *reinterpret_cast<const float4*>(xp + 4);
            const _Float16* wc = wb + (size_t)(c0 + 2) * 6144;
            #pragma unroll
            for (int n = 0; n < 3; ++n)
                w0[n] = *reinterpret_cast<const half8*>(wc + n * 512);
        }
        {   // compute chunk c0+1 (buf1)
            const half8 af = { (_Float16)xa1.x, (_Float16)xa1.y, (_Float16)xa1.z, (_Float16)xa1.w,
                               (_Float16)xb1.x, (_Float16)xb1.y, (_Float16)xb1.z, (_Float16)xb1.w };
            #pragma unroll
            for (int n = 0; n < 3; ++n)
                acc[n] = __builtin_amdgcn_mfma_f32_16x16x32_f16(af, w1[n], acc[n], 0, 0, 0);
        }
        {   // issue loads for chunk c0+3 into buf1
            const float* xp = xrow + (c0 + 3) * 32;
            xa1 = *reinterpret_cast<const float4*>(xp);
            xb1 = *reinterpret_cast<const float4*>(xp + 4);
            const _Float16* wc = wb + (size_t)(c0 + 3) * 6144;
            #pragma unroll
            for (int n = 0; n < 3; ++n)
                w1[n] = *reinterpret_cast<const half8*>(wc + n * 512);
        }
    }
    {   // epilogue: chunk 30 (buf0)
        const half8 af = { (_Float16)xa0.x, (_Float16)xa0.y, (_Float16)xa0.z, (_Float16)xa0.w,
                           (_Float16)xb0.x, (_Float16)xb0.y, (_Float16)xb0.z, (_Float16)xb0.w };
        #pragma unroll
        for (int n = 0; n < 3; ++n)
            acc[n] = __builtin_amdgcn_mfma_f32_16x16x32_f16(af, w0[n], acc[n], 0, 0, 0);
    }
    {   // epilogue: chunk 31 (buf1)
        const half8 af = { (_Float16)xa1.x, (_Float16)xa1.y, (_Float16)xa1.z, (_Float16)xa1.w,
                           (_Float16)xb1.x, (_Float16)xb1.y, (_Float16)xb1.z, (_Float16)xb1.w };
        #pragma unroll
        for (int n = 0; n < 3; ++n)
            acc[n] = __builtin_amdgcn_mfma_f32_16x16x32_f16(af, w1[n], acc[n], 0, 0, 0);
    }

    // epilogue: col = nq*48 + n*16 + fm  (each frag wholly inside q, k, or v)
    #pragma unroll
    for (int n = 0; n < 3; ++n) {
        const int col = nq * 48 + n * 16 + fm;
        if (col < 64) {                          // q: row-major
            #pragma unroll
            for (int r = 0; r < 4; ++r)
                q16[(size_t)(m_base + fr + r) * HH + col] = (_Float16)acc[n][r];
        } else if (col < 128) {                  // k: fragment-packed
            const int h = col - 64;
            _Float16* kp = &Kp[(size_t)(mtile * 2 + (h >> 5)) * 512 + (h & 31)];
            #pragma unroll
            for (int r = 0; r < 4; ++r)
                kp[(fr + r) * 32] = (_Float16)acc[n][r];
        } else {                                 // v: fragment-packed (transposed)
            const int h = col - 128;
            const half4 pk = { (_Float16)acc[n][0], (_Float16)acc[n][1],
                               (_Float16)acc[n][2], (_Float16)acc[n][3] };
            *reinterpret_cast<half4*>(
                &Vp[(size_t)((mtile >> 2) * 4 + (h >> 4)) * 1024 +
                    ((mtile >> 1) & 1) * 512 + fm * 32 + (mtile & 1) * 16 + fr]) = pk;
        }
    }
}

// ---------------------------------------------------------------------------
// Kernel 2: barrier-free split-K causal attention. 3072 single-wave blocks =
// 128 q-tiles(16 rows) x 8 batches x 3 key-segments, longest-first.
// 12 waves/CU (3/SIMD). K/V B-frags: contiguous 1 KB loads from Kp/Vp
// (L2-hot). P via 2.2 KB wave-private LDS (lgkmcnt ordering only).
// DPP row-max + ones-MFMA row-sum. Partials: seg0 -> out (fp32), segs 1,2 ->
// fp16 Op; (m,l) -> ml.
// ---------------------------------------------------------------------------
__global__ __launch_bounds__(64, 4)
void attn7(const _Float16* __restrict__ q16, const _Float16* __restrict__ Kp,
           const _Float16* __restrict__ Vp, float* __restrict__ out,
           _Float16* __restrict__ Op, float* __restrict__ ml)
{
    __shared__ _Float16 Ps[16 * 68];

    const int bid = blockIdx.x;           // 0..3071
    const int it  = 127 - bid / 24;       // longest q-tiles first
    const int sub = bid - (127 - it) * 24;
    const int b   = sub & 7;
    const int s   = sub >> 3;             // segment 0..2

    const int lane = threadIdx.x;
    const int fm = lane & 15;
    const int fq = lane >> 4;
    const int fk = fq * 8;
    const int fr = fq * 4;

    const int Ji = (it >> 2) + 1;
    const int qq = Ji / 3, rem = Ji - qq * 3;
    const int cnt   = qq + (s < rem ? 1 : 0);
    const int start = s * qq + (s < rem ? s : rem);

    const _Float16* __restrict__ kpb = Kp + (size_t)b * TT * HH;
    const _Float16* __restrict__ vpb = Vp + (size_t)b * TT * HH;

    const int qrow = (b * 128 + it) * 16 + fm;
    const half8 qf0 = *reinterpret_cast<const half8*>(&q16[(size_t)qrow * HH + fk]);
    const half8 qf1 = *reinterpret_cast<const half8*>(&q16[(size_t)qrow * HH + 32 + fk]);

    floatx4 O[4], lacc;
    float m_r[4];
    #pragma unroll
    for (int r = 0; r < 4; ++r) {
        m_r[r] = -3.0e38f;
        lacc[r] = 0.0f;
        #pragma unroll
        for (int ht = 0; ht < 4; ++ht) O[ht][r] = 0.0f;
    }
    const half8 ones = { (_Float16)1.f, (_Float16)1.f, (_Float16)1.f, (_Float16)1.f,
                         (_Float16)1.f, (_Float16)1.f, (_Float16)1.f, (_Float16)1.f };

    const int loff = fm * 32 + fk;        // per-lane offset inside a packed frag

    for (int js = 0; js < cnt; ++js) {
        const int jj = start + js;

        // ---- S = Q K^T : 8 MFMAs, B-frags = contiguous 1KB packed loads ----
        floatx4 sa[4];
        #pragma unroll
        for (int nt = 0; nt < 4; ++nt) {
            #pragma unroll
            for (int r = 0; r < 4; ++r) sa[nt][r] = 0.0f;
            const _Float16* kp = &kpb[(size_t)(jj * 4 + nt) * 1024];
            const half8 b0 = *reinterpret_cast<const half8*>(kp + loff);
            const half8 b1 = *reinterpret_cast<const half8*>(kp + 512 + loff);
            sa[nt] = __builtin_amdgcn_mfma_f32_16x16x32_f16(qf0, b0, sa[nt], 0, 0, 0);
            sa[nt] = __builtin_amdgcn_mfma_f32_16x16x32_f16(qf1, b1, sa[nt], 0, 0, 0);
        }

        // ---- causal mask (only the diagonal tile) ----
        if (jj == (it >> 2)) {
            const int rbase = it * 16 + fr;
            #pragma unroll
            for (int nt = 0; nt < 4; ++nt) {
                const int col = jj * 64 + nt * 16 + fm;
                #pragma unroll
                for (int r = 0; r < 4; ++r)
                    if (col > rbase + r) sa[nt][r] = -3.0e38f;
            }
        }

        // ---- online softmax: DPP row-max; row-sum via ones-MFMA ----
        #pragma unroll
        for (int r = 0; r < 4; ++r) {
            float mx = fmaxf(fmaxf(sa[0][r], sa[1][r]), fmaxf(sa[2][r], sa[3][r]));
            mx = rowmax16(mx);
            const float mn = fmaxf(m_r[r], mx);
            const float alpha = __expf(m_r[r] - mn);
            m_r[r] = mn;
            _Float16* pp = &Ps[(fr + r) * 68 + fm];
            pp[0]  = (_Float16)__expf(sa[0][r] - mn);
            pp[16] = (_Float16)__expf(sa[1][r] - mn);
            pp[32] = (_Float16)__expf(sa[2][r] - mn);
            pp[48] = (_Float16)__expf(sa[3][r] - mn);
            lacc[r] *= alpha;
            O[0][r] *= alpha; O[1][r] *= alpha; O[2][r] *= alpha; O[3][r] *= alpha;
        }
        // wave-private LDS: lgkmcnt ordering suffices, no barrier

        // ---- O += P V, l += P 1 : 10 MFMAs ----
        #pragma unroll
        for (int ch = 0; ch < 2; ++ch) {
            const half8 pa = *reinterpret_cast<const half8*>(&Ps[fm * 68 + ch * 32 + fk]);
            lacc = __builtin_amdgcn_mfma_f32_16x16x32_f16(pa, ones, lacc, 0, 0, 0);
            #pragma unroll
            for (int ht = 0; ht < 4; ++ht) {
                const half8 vb = *reinterpret_cast<const half8*>(
                    &vpb[(size_t)(jj * 4 + ht) * 1024 + ch * 512 + loff]);
                O[ht] = __builtin_amdgcn_mfma_f32_16x16x32_f16(pa, vb, O[ht], 0, 0, 0);
            }
        }
    }

    // ---- epilogue: write segment partial (unnormalized O, m, l) ----
    #pragma unroll
    for (int r = 0; r < 4; ++r) {
        const int grow = (b * 128 + it) * 16 + fr + r;
        if (s == 0) {
            #pragma unroll
            for (int ht = 0; ht < 4; ++ht)
                out[(size_t)grow * HH + ht * 16 + fm] = O[ht][r];
        } else {
            #pragma unroll
            for (int ht = 0; ht < 4; ++ht)
                Op[((size_t)(s - 1) * MM + grow) * HH + ht * 16 + fm] = (_Float16)O[ht][r];
        }
        if (fm == 0) {
            ml[((size_t)s * MM + grow) * 2 + 0] = m_r[r];
            ml[((size_t)s * MM + grow) * 2 + 1] = lacc[r];
        }
    }
}

// ---------------------------------------------------------------------------
// Kernel 3: flash-decode combine of the 3 segment partials.
// ---------------------------------------------------------------------------
__global__ __launch_bounds__(256)
void combine(float* __restrict__ out, const _Float16* __restrict__ Op,
             const float* __restrict__ ml)
{
    const int tid  = threadIdx.x;
    const int grow = blockIdx.x * 64 + (tid >> 2);
    const int c0   = (tid & 3) * 16;

    const float m0 = ml[(size_t)grow * 2 + 0];
    const float l0 = ml[(size_t)grow * 2 + 1];
    const float m1 = ml[((size_t)MM + grow) * 2 + 0];
    const float l1 = ml[((size_t)MM + grow) * 2 + 1];
    const float m2 = ml[((size_t)2 * MM + grow) * 2 + 0];
    const float l2 = ml[((size_t)2 * MM + grow) * 2 + 1];

    const float M  = fmaxf(m0, fmaxf(m1, m2));
    const float w0 = __expf(m0 - M);
    const float w1 = __expf(m1 - M);
    const float w2 = __expf(m2 - M);
    const float inv = 1.0f / (w0 * l0 + w1 * l1 + w2 * l2);

    #pragma unroll
    for (int i = 0; i < 16; i += 4) {
        float4 o0 = *reinterpret_cast<float4*>(&out[(size_t)grow * HH + c0 + i]);
        const half4 h1 = *reinterpret_cast<const half4*>(&Op[(size_t)grow * HH + c0 + i]);
        const half4 h2 = *reinterpret_cast<const half4*>(&Op[(size_t)MM * HH + (size_t)grow * HH + c0 + i]);
        o0.x = (w0 * o0.x + w1 * (float)h1[0] + w2 * (float)h2[0]) * inv;
        o0.y = (w0 * o0.y + w1 * (float)h1[1] + w2 * (float)h2[1]) * inv;
        o0.z = (w0 * o0.z + w1 * (float)h1[2] + w2 * (float)h2[2]) * inv;
        o0.w = (w0 * o0.w + w1 * (float)h1[3] + w2 * (float)h2[3]) * inv;
        *reinterpret_cast<float4*>(&out[(size_t)grow * HH + c0 + i]) = o0;
    }
}

// ---------------------------------------------------------------------------
extern "C" void kernel_launch(void* const* d_in, const int* in_sizes, int n_in,
                              void* d_out, int out_size, void* d_ws, size_t ws_size,
                              hipStream_t stream)
{
    (void)in_sizes; (void)n_in; (void)out_size; (void)ws_size;

    const float* x  = (const float*)d_in[0];
    const float* Wk = (const float*)d_in[1];
    const float* Wq = (const float*)d_in[2];
    const float* Wv = (const float*)d_in[3];
    float* out = (float*)d_out;

    _Float16* base = (_Float16*)d_ws;
    _Float16* q16 = base;                                  // MM*HH halves
    _Float16* Kp  = base + (size_t)MM * HH;                // MM*HH
    _Float16* Vp  = base + (size_t)2 * MM * HH;            // MM*HH
    _Float16* Wp  = base + (size_t)3 * MM * HH;            // 192*1024
    _Float16* Op  = Wp + 192 * 1024;                       // 2*MM*HH
    float*    ml  = (float*)(Op + (size_t)2 * MM * HH);    // 3*MM*2 floats

    w_pack<<<dim3(96), dim3(256), 0, stream>>>(Wk, Wq, Wv, Wp);
    qkv8<<<dim3(4096), dim3(64), 0, stream>>>(x, Wp, q16, Kp, Vp);
    attn7<<<dim3(3072), dim3(64), 0, stream>>>(q16, Kp, Vp, out, Op, ml);
    combine<<<dim3(256), dim3(256), 0, stream>>>(out, Op, ml);
}

// Round 2
// 151.013 us; speedup vs baseline: 1.1020x; 1.1020x over previous
//
#include <hip/hip_runtime.h>

#define BB 8
#define TT 2048
#define CC 1024
#define HH 64
#define MM (BB * TT)   // 16384 rows

typedef _Float16 half8 __attribute__((ext_vector_type(8)));
typedef _Float16 half4 __attribute__((ext_vector_type(4)));
typedef float floatx4 __attribute__((ext_vector_type(4)));

// 16-lane all-reduce max via DPP row-rotate butterfly (VALU pipe, no LDS).
template <int CTRL>
__device__ __forceinline__ float dpp_max_step(float x)
{
    union { float f; int i; } u, v;
    u.f = x;
    v.i = __builtin_amdgcn_update_dpp(u.i, u.i, CTRL, 0xf, 0xf, false);
    return fmaxf(x, v.f);
}
__device__ __forceinline__ float rowmax16(float x)
{
    x = dpp_max_step<0x128>(x);   // ROW_ROR:8
    x = dpp_max_step<0x124>(x);   // ROW_ROR:4
    x = dpp_max_step<0x122>(x);   // ROW_ROR:2
    x = dpp_max_step<0x121>(x);   // ROW_ROR:1
    return x;
}

// async global->LDS, 16B per lane; LDS dest is wave-uniform base + lane*16.
__device__ __forceinline__ void gll16(const float* g, float* l)
{
    __builtin_amdgcn_global_load_lds(
        (const __attribute__((address_space(1))) unsigned int*)g,
        (__attribute__((address_space(3))) unsigned int*)l, 16, 0, 0);
}

#define MEMFENCE asm volatile("" ::: "memory")

// ---------------------------------------------------------------------------
// Kernel 0: pack W into chunk-major fp16 layout:
//   Wp[(c*192 + row)*32 + kk] = Wscaled[row][c*32 + kk]   (c = K-chunk of 32)
// rows 0..63 = Wq*8 (sqrt(H) fold), 64..127 = Wk, 128..191 = Wv.
// A 16x16x32 B-fragment (16 rows x k32) is contiguous 1 KB.
// ---------------------------------------------------------------------------
__global__ __launch_bounds__(256)
void w_pack(const float* __restrict__ Wk, const float* __restrict__ Wq,
            const float* __restrict__ Wv, _Float16* __restrict__ Wp)
{
    const int idx = (blockIdx.x * 256 + threadIdx.x) * 8;  // 0..196600
    const int c   = idx / 6144;          // 192*32 = 6144
    const int rm  = idx - c * 6144;
    const int row = rm >> 5;             // 0..191
    const int kk  = rm & 31;             // 0,8,16,24
    const int which = row >> 6;
    const float* __restrict__ src = (which == 0) ? Wq : ((which == 1) ? Wk : Wv);
    const float scale = (which == 0) ? 8.0f : 1.0f;
    const int srow = row & 63;
    const int k = c * 32 + kk;
    const float4 a = *reinterpret_cast<const float4*>(&src[srow * 1024 + k]);
    const float4 b = *reinterpret_cast<const float4*>(&src[srow * 1024 + k + 4]);
    const half8 o = { (_Float16)(a.x * scale), (_Float16)(a.y * scale),
                      (_Float16)(a.z * scale), (_Float16)(a.w * scale),
                      (_Float16)(b.x * scale), (_Float16)(b.y * scale),
                      (_Float16)(b.z * scale), (_Float16)(b.w * scale) };
    *reinterpret_cast<half8*>(&Wp[idx]) = o;
}

// ---------------------------------------------------------------------------
// Kernel 1: QKV projection, v9 — LDS-staged block GEMM.
// 256 blocks x 512 threads (8 waves) = 1 block/CU. Block tile: 64 rows x 192
// cols, K-chunks of 32. x staged via global_load_lds (width 16) into a
// 4-deep LDS ring (8 KB/chunk fp32), with SOURCE-swizzled per-lane global
// addresses (16B slot ^= row&7) so linear LDS dest gives conflict-free
// strided ds_read_b128. gll issued at distance 3, W (L2-hot, reg dbuf) at
// distance 1, counted vmcnt(8) + raw s_barrier per chunk (loads stay in
// flight across barriers). Wave w: rows (w>>2)*32, cols (w&3)*48 -> 6 MFMA
// per chunk per wave. Traffic: x read ONCE from HBM (64 MB), W 96 MB L2-hot.
// Outputs identical layouts to v7: q16 row-major; Kp/Vp fragment-packed.
// ---------------------------------------------------------------------------
__global__ __launch_bounds__(512, 2)
void qkv9(const float* __restrict__ x, const _Float16* __restrict__ Wp,
          _Float16* __restrict__ q16, _Float16* __restrict__ Kp,
          _Float16* __restrict__ Vp)
{
    __shared__ float xs[4][64][32];      // 32 KB ring, NO padding (gll linear)

    const int tid  = threadIdx.x;
    const int lane = tid & 63;
    const int w    = tid >> 6;           // 0..7
    const int blk  = blockIdx.x;         // 0..255
    const int m_base = blk * 64;
    const int fm = lane & 15;
    const int fq = lane >> 4;
    const int fk = fq * 8;
    const int fr = fq * 4;
    const int wm = w >> 2;               // row half: 0,1
    const int wn = w & 3;                // col group: 0..3

    // staging: wave w stages rows w*8..w*8+7; lane l -> row w*8+(l>>3),
    // physical 16B slot (l&7) receives logical slot (l&7)^(l>>3).
    const float* gsrc = &x[(size_t)(m_base + w * 8 + (lane >> 3)) * CC
                           + ((lane & 7) ^ (lane >> 3)) * 4];
    float* ldst = &xs[0][w * 8][0];      // + buf*2048 floats

    const _Float16* wb = &Wp[(wn * 48 + fm) * 32 + fk];

    floatx4 acc[2][3];
    #pragma unroll
    for (int a = 0; a < 2; ++a)
        #pragma unroll
        for (int n = 0; n < 3; ++n)
            #pragma unroll
            for (int r = 0; r < 4; ++r) acc[a][n][r] = 0.0f;

    half8 wA[3], wB[3];

    // ---- prologue: W(0) -> wA; gll chunks 0,1,2 ----
    #pragma unroll
    for (int n = 0; n < 3; ++n)
        wA[n] = *reinterpret_cast<const half8*>(wb + n * 512);
    MEMFENCE;
    gll16(gsrc + 0 * 32, ldst + 0 * 2048);
    gll16(gsrc + 1 * 32, ldst + 1 * 2048);
    gll16(gsrc + 2 * 32, ldst + 2 * 2048);
    asm volatile("s_waitcnt vmcnt(2)" ::: "memory");   // gll(0)+W(0) done
    __builtin_amdgcn_s_barrier();
    MEMFENCE;

    // One chunk: [issue W(c+1)] [issue gll(c+3)] [compute c] [vmcnt(N)] [bar]
#define QKV_ITER(c, WUSE, WLOAD, DO_W, DO_X, NWAIT)                            \
    {                                                                          \
        if (DO_W) {                                                            \
            _Pragma("unroll")                                                  \
            for (int n = 0; n < 3; ++n)                                        \
                WLOAD[n] = *reinterpret_cast<const half8*>(                    \
                    wb + (size_t)((c) + 1) * 6144 + n * 512);                  \
        }                                                                      \
        MEMFENCE;                                                              \
        if (DO_X) gll16(gsrc + ((c) + 3) * 32, ldst + (((c) + 3) & 3) * 2048); \
        _Pragma("unroll")                                                      \
        for (int a = 0; a < 2; ++a) {                                          \
            const int rr = wm * 32 + a * 16 + fm;                              \
            const float* rowp = &xs[(c) & 3][rr][0];                           \
            const int sw = fm & 7;                                             \
            const float4 v0 = *reinterpret_cast<const float4*>(                \
                rowp + ((fq * 2 + 0) ^ sw) * 4);                               \
            const float4 v1 = *reinterpret_cast<const float4*>(                \
                rowp + ((fq * 2 + 1) ^ sw) * 4);                               \
            const half8 af = { (_Float16)v0.x, (_Float16)v0.y,                 \
                               (_Float16)v0.z, (_Float16)v0.w,                 \
                               (_Float16)v1.x, (_Float16)v1.y,                 \
                               (_Float16)v1.z, (_Float16)v1.w };               \
            _Pragma("unroll")                                                  \
            for (int n = 0; n < 3; ++n)                                        \
                acc[a][n] = __builtin_amdgcn_mfma_f32_16x16x32_f16(            \
                    af, WUSE[n], acc[a][n], 0, 0, 0);                          \
        }                                                                      \
        asm volatile("s_waitcnt vmcnt(" #NWAIT ")" ::: "memory");              \
        __builtin_amdgcn_s_barrier();                                          \
        MEMFENCE;                                                              \
    }

    for (int cc = 0; cc < 28; cc += 2) {
        QKV_ITER(cc,     wA, wB, true,  true,  8);
        QKV_ITER(cc + 1, wB, wA, true,  true,  8);
    }
    QKV_ITER(28, wA, wB, true,  true,  8);   // issues W(29), gll(31)
    QKV_ITER(29, wB, wA, true,  false, 4);   // issues W(30); gll(30) done
    QKV_ITER(30, wA, wB, true,  false, 0);   // issues W(31); gll(31) done
    QKV_ITER(31, wB, wA, false, false, 0);   // pure compute
#undef QKV_ITER

    // ---- epilogue: col = wn*48 + n*16 + fm, 16-row tile mt ----
    #pragma unroll
    for (int a = 0; a < 2; ++a) {
        const int mt = blk * 4 + wm * 2 + a;
        #pragma unroll
        for (int n = 0; n < 3; ++n) {
            const int col = wn * 48 + n * 16 + fm;
            if (col < 64) {                          // q: row-major
                #pragma unroll
                for (int r = 0; r < 4; ++r)
                    q16[(size_t)(mt * 16 + fr + r) * HH + col] = (_Float16)acc[a][n][r];
            } else if (col < 128) {                  // k: fragment-packed
                const int h = col - 64;
                _Float16* kp = &Kp[(size_t)(mt * 2 + (h >> 5)) * 512 + (h & 31)];
                #pragma unroll
                for (int r = 0; r < 4; ++r)
                    kp[(fr + r) * 32] = (_Float16)acc[a][n][r];
            } else {                                 // v: fragment-packed (transposed)
                const int h = col - 128;
                const half4 pk = { (_Float16)acc[a][n][0], (_Float16)acc[a][n][1],
                                   (_Float16)acc[a][n][2], (_Float16)acc[a][n][3] };
                *reinterpret_cast<half4*>(
                    &Vp[(size_t)((mt >> 2) * 4 + (h >> 4)) * 1024 +
                        ((mt >> 1) & 1) * 512 + fm * 32 + (mt & 1) * 16 + fr]) = pk;
            }
        }
    }
}

// ---------------------------------------------------------------------------
// Kernel 2: barrier-free split-K causal attention. 3072 single-wave blocks =
// 128 q-tiles(16 rows) x 8 batches x 3 key-segments, longest-first.
// 12 waves/CU (3/SIMD). K/V B-frags: contiguous 1 KB loads from Kp/Vp
// (L2-hot). P via 2.2 KB wave-private LDS (lgkmcnt ordering only).
// DPP row-max + ones-MFMA row-sum. Partials: seg0 -> out (fp32), segs 1,2 ->
// fp16 Op; (m,l) -> ml.
// ---------------------------------------------------------------------------
__global__ __launch_bounds__(64, 4)
void attn7(const _Float16* __restrict__ q16, const _Float16* __restrict__ Kp,
           const _Float16* __restrict__ Vp, float* __restrict__ out,
           _Float16* __restrict__ Op, float* __restrict__ ml)
{
    __shared__ _Float16 Ps[16 * 68];

    const int bid = blockIdx.x;           // 0..3071
    const int it  = 127 - bid / 24;       // longest q-tiles first
    const int sub = bid - (127 - it) * 24;
    const int b   = sub & 7;
    const int s   = sub >> 3;             // segment 0..2

    const int lane = threadIdx.x;
    const int fm = lane & 15;
    const int fq = lane >> 4;
    const int fk = fq * 8;
    const int fr = fq * 4;

    const int Ji = (it >> 2) + 1;
    const int qq = Ji / 3, rem = Ji - qq * 3;
    const int cnt   = qq + (s < rem ? 1 : 0);
    const int start = s * qq + (s < rem ? s : rem);

    const _Float16* __restrict__ kpb = Kp + (size_t)b * TT * HH;
    const _Float16* __restrict__ vpb = Vp + (size_t)b * TT * HH;

    const int qrow = (b * 128 + it) * 16 + fm;
    const half8 qf0 = *reinterpret_cast<const half8*>(&q16[(size_t)qrow * HH + fk]);
    const half8 qf1 = *reinterpret_cast<const half8*>(&q16[(size_t)qrow * HH + 32 + fk]);

    floatx4 O[4], lacc;
    float m_r[4];
    #pragma unroll
    for (int r = 0; r < 4; ++r) {
        m_r[r] = -3.0e38f;
        lacc[r] = 0.0f;
        #pragma unroll
        for (int ht = 0; ht < 4; ++ht) O[ht][r] = 0.0f;
    }
    const half8 ones = { (_Float16)1.f, (_Float16)1.f, (_Float16)1.f, (_Float16)1.f,
                         (_Float16)1.f, (_Float16)1.f, (_Float16)1.f, (_Float16)1.f };

    const int loff = fm * 32 + fk;        // per-lane offset inside a packed frag

    for (int js = 0; js < cnt; ++js) {
        const int jj = start + js;

        // ---- S = Q K^T : 8 MFMAs, B-frags = contiguous 1KB packed loads ----
        floatx4 sa[4];
        #pragma unroll
        for (int nt = 0; nt < 4; ++nt) {
            #pragma unroll
            for (int r = 0; r < 4; ++r) sa[nt][r] = 0.0f;
            const _Float16* kp = &kpb[(size_t)(jj * 4 + nt) * 1024];
            const half8 b0 = *reinterpret_cast<const half8*>(kp + loff);
            const half8 b1 = *reinterpret_cast<const half8*>(kp + 512 + loff);
            sa[nt] = __builtin_amdgcn_mfma_f32_16x16x32_f16(qf0, b0, sa[nt], 0, 0, 0);
            sa[nt] = __builtin_amdgcn_mfma_f32_16x16x32_f16(qf1, b1, sa[nt], 0, 0, 0);
        }

        // ---- causal mask (only the diagonal tile) ----
        if (jj == (it >> 2)) {
            const int rbase = it * 16 + fr;
            #pragma unroll
            for (int nt = 0; nt < 4; ++nt) {
                const int col = jj * 64 + nt * 16 + fm;
                #pragma unroll
                for (int r = 0; r < 4; ++r)
                    if (col > rbase + r) sa[nt][r] = -3.0e38f;
            }
        }

        // ---- online softmax: DPP row-max; row-sum via ones-MFMA ----
        #pragma unroll
        for (int r = 0; r < 4; ++r) {
            float mx = fmaxf(fmaxf(sa[0][r], sa[1][r]), fmaxf(sa[2][r], sa[3][r]));
            mx = rowmax16(mx);
            const float mn = fmaxf(m_r[r], mx);
            const float alpha = __expf(m_r[r] - mn);
            m_r[r] = mn;
            _Float16* pp = &Ps[(fr + r) * 68 + fm];
            pp[0]  = (_Float16)__expf(sa[0][r] - mn);
            pp[16] = (_Float16)__expf(sa[1][r] - mn);
            pp[32] = (_Float16)__expf(sa[2][r] - mn);
            pp[48] = (_Float16)__expf(sa[3][r] - mn);
            lacc[r] *= alpha;
            O[0][r] *= alpha; O[1][r] *= alpha; O[2][r] *= alpha; O[3][r] *= alpha;
        }
        // wave-private LDS: lgkmcnt ordering suffices, no barrier

        // ---- O += P V, l += P 1 : 10 MFMAs ----
        #pragma unroll
        for (int ch = 0; ch < 2; ++ch) {
            const half8 pa = *reinterpret_cast<const half8*>(&Ps[fm * 68 + ch * 32 + fk]);
            lacc = __builtin_amdgcn_mfma_f32_16x16x32_f16(pa, ones, lacc, 0, 0, 0);
            #pragma unroll
            for (int ht = 0; ht < 4; ++ht) {
                const half8 vb = *reinterpret_cast<const half8*>(
                    &vpb[(size_t)(jj * 4 + ht) * 1024 + ch * 512 + loff]);
                O[ht] = __builtin_amdgcn_mfma_f32_16x16x32_f16(pa, vb, O[ht], 0, 0, 0);
            }
        }
    }

    // ---- epilogue: write segment partial (unnormalized O, m, l) ----
    #pragma unroll
    for (int r = 0; r < 4; ++r) {
        const int grow = (b * 128 + it) * 16 + fr + r;
        if (s == 0) {
            #pragma unroll
            for (int ht = 0; ht < 4; ++ht)
                out[(size_t)grow * HH + ht * 16 + fm] = O[ht][r];
        } else {
            #pragma unroll
            for (int ht = 0; ht < 4; ++ht)
                Op[((size_t)(s - 1) * MM + grow) * HH + ht * 16 + fm] = (_Float16)O[ht][r];
        }
        if (fm == 0) {
            ml[((size_t)s * MM + grow) * 2 + 0] = m_r[r];
            ml[((size_t)s * MM + grow) * 2 + 1] = lacc[r];
        }
    }
}

// ---------------------------------------------------------------------------
// Kernel 3: flash-decode combine of the 3 segment partials.
// ---------------------------------------------------------------------------
__global__ __launch_bounds__(256)
void combine(float* __restrict__ out, const _Float16* __restrict__ Op,
             const float* __restrict__ ml)
{
    const int tid  = threadIdx.x;
    const int grow = blockIdx.x * 64 + (tid >> 2);
    const int c0   = (tid & 3) * 16;

    const float m0 = ml[(size_t)grow * 2 + 0];
    const float l0 = ml[(size_t)grow * 2 + 1];
    const float m1 = ml[((size_t)MM + grow) * 2 + 0];
    const float l1 = ml[((size_t)MM + grow) * 2 + 1];
    const float m2 = ml[((size_t)2 * MM + grow) * 2 + 0];
    const float l2 = ml[((size_t)2 * MM + grow) * 2 + 1];

    const float M  = fmaxf(m0, fmaxf(m1, m2));
    const float w0 = __expf(m0 - M);
    const float w1 = __expf(m1 - M);
    const float w2 = __expf(m2 - M);
    const float inv = 1.0f / (w0 * l0 + w1 * l1 + w2 * l2);

    #pragma unroll
    for (int i = 0; i < 16; i += 4) {
        float4 o0 = *reinterpret_cast<float4*>(&out[(size_t)grow * HH + c0 + i]);
        const half4 h1 = *reinterpret_cast<const half4*>(&Op[(size_t)grow * HH + c0 + i]);
        const half4 h2 = *reinterpret_cast<const half4*>(&Op[(size_t)MM * HH + (size_t)grow * HH + c0 + i]);
        o0.x = (w0 * o0.x + w1 * (float)h1[0] + w2 * (float)h2[0]) * inv;
        o0.y = (w0 * o0.y + w1 * (float)h1[1] + w2 * (float)h2[1]) * inv;
        o0.z = (w0 * o0.z + w1 * (float)h1[2] + w2 * (float)h2[2]) * inv;
        o0.w = (w0 * o0.w + w1 * (float)h1[3] + w2 * (float)h2[3]) * inv;
        *reinterpret_cast<float4*>(&out[(size_t)grow * HH + c0 + i]) = o0;
    }
}

// ---------------------------------------------------------------------------
extern "C" void kernel_launch(void* const* d_in, const int* in_sizes, int n_in,
                              void* d_out, int out_size, void* d_ws, size_t ws_size,
                              hipStream_t stream)
{
    (void)in_sizes; (void)n_in; (void)out_size; (void)ws_size;

    const float* x  = (const float*)d_in[0];
    const float* Wk = (const float*)d_in[1];
    const float* Wq = (const float*)d_in[2];
    const float* Wv = (const float*)d_in[3];
    float* out = (float*)d_out;

    _Float16* base = (_Float16*)d_ws;
    _Float16* q16 = base;                                  // MM*HH halves
    _Float16* Kp  = base + (size_t)MM * HH;                // MM*HH
    _Float16* Vp  = base + (size_t)2 * MM * HH;            // MM*HH
    _Float16* Wp  = base + (size_t)3 * MM * HH;            // 192*1024
    _Float16* Op  = Wp + 192 * 1024;                       // 2*MM*HH
    float*    ml  = (float*)(Op + (size_t)2 * MM * HH);    // 3*MM*2 floats

    w_pack<<<dim3(96), dim3(256), 0, stream>>>(Wk, Wq, Wv, Wp);
    qkv9<<<dim3(256), dim3(512), 0, stream>>>(x, Wp, q16, Kp, Vp);
    attn7<<<dim3(3072), dim3(64), 0, stream>>>(q16, Kp, Vp, out, Op, ml);
    combine<<<dim3(256), dim3(256), 0, stream>>>(out, Op, ml);
}

// Round 4
// 149.992 us; speedup vs baseline: 1.1095x; 1.0068x over previous
//
#include <hip/hip_runtime.h>

#define BB 8
#define TT 2048
#define CC 1024
#define HH 64
#define MM (BB * TT)   // 16384 rows

typedef _Float16 half8 __attribute__((ext_vector_type(8)));
typedef _Float16 half4 __attribute__((ext_vector_type(4)));
typedef float floatx4 __attribute__((ext_vector_type(4)));

// 16-lane all-reduce max via DPP row-rotate butterfly (VALU pipe, no LDS).
template <int CTRL>
__device__ __forceinline__ float dpp_max_step(float x)
{
    union { float f; int i; } u, v;
    u.f = x;
    v.i = __builtin_amdgcn_update_dpp(u.i, u.i, CTRL, 0xf, 0xf, false);
    return fmaxf(x, v.f);
}
__device__ __forceinline__ float rowmax16(float x)
{
    x = dpp_max_step<0x128>(x);   // ROW_ROR:8
    x = dpp_max_step<0x124>(x);   // ROW_ROR:4
    x = dpp_max_step<0x122>(x);   // ROW_ROR:2
    x = dpp_max_step<0x121>(x);   // ROW_ROR:1
    return x;
}

// async global->LDS, 16B per lane; LDS dest is wave-uniform base + lane*16.
__device__ __forceinline__ void gll16(const float* g, float* l)
{
    __builtin_amdgcn_global_load_lds(
        (const __attribute__((address_space(1))) unsigned int*)g,
        (__attribute__((address_space(3))) unsigned int*)l, 16, 0, 0);
}

#define MEMFENCE asm volatile("" ::: "memory")

// ---------------------------------------------------------------------------
// Kernel 0: pack W into chunk-major fp16 layout:
//   Wp[(c*192 + row)*32 + kk] = Wscaled[row][c*32 + kk]   (c = K-chunk of 32)
// rows 0..63 = Wq*8 (sqrt(H) fold), 64..127 = Wk, 128..191 = Wv.
// A 16x16x32 B-fragment (16 rows x k32) is contiguous 1 KB.
// ---------------------------------------------------------------------------
__global__ __launch_bounds__(256)
void w_pack(const float* __restrict__ Wk, const float* __restrict__ Wq,
            const float* __restrict__ Wv, _Float16* __restrict__ Wp)
{
    const int idx = (blockIdx.x * 256 + threadIdx.x) * 8;  // 0..196600
    const int c   = idx / 6144;          // 192*32 = 6144
    const int rm  = idx - c * 6144;
    const int row = rm >> 5;             // 0..191
    const int kk  = rm & 31;             // 0,8,16,24
    const int which = row >> 6;
    const float* __restrict__ src = (which == 0) ? Wq : ((which == 1) ? Wk : Wv);
    const float scale = (which == 0) ? 8.0f : 1.0f;
    const int srow = row & 63;
    const int k = c * 32 + kk;
    const float4 a = *reinterpret_cast<const float4*>(&src[srow * 1024 + k]);
    const float4 b = *reinterpret_cast<const float4*>(&src[srow * 1024 + k + 4]);
    const half8 o = { (_Float16)(a.x * scale), (_Float16)(a.y * scale),
                      (_Float16)(a.z * scale), (_Float16)(a.w * scale),
                      (_Float16)(b.x * scale), (_Float16)(b.y * scale),
                      (_Float16)(b.z * scale), (_Float16)(b.w * scale) };
    *reinterpret_cast<half8*>(&Wp[idx]) = o;
}

// ---------------------------------------------------------------------------
// Kernel 1: QKV projection, v10 — v9 LDS-staged block GEMM + PER-BLOCK K-SKEW.
// Partition-camping fix: v7/v9 both ran at 44 us independent of HBM traffic
// because all waves machine-wide read x at the SAME column offset c*128 of
// 4KB-strided rows (one 128B slice of every 4KB page live at a time -> ~1/8
// of memory channels active, BW collapsed to ~0.8 TB/s). Block blk now
// iterates physical chunks p = (i + blk%32) & 31: the 32 blocks of each XCD
// cover all 32 column offsets simultaneously -> full channel spread.
// (fp32 K-accumulation is order-independent.)
// Everything else identical to v9: 256 blocks x 8 waves, 4-deep LDS ring,
// gll dist-3, W reg-dbuf dist-1, counted vmcnt(8) + raw s_barrier per chunk.
// ---------------------------------------------------------------------------
__global__ __launch_bounds__(512, 2)
void qkv10(const float* __restrict__ x, const _Float16* __restrict__ Wp,
           _Float16* __restrict__ q16, _Float16* __restrict__ Kp,
           _Float16* __restrict__ Vp)
{
    __shared__ float xs[4][64][32];      // 32 KB ring, NO padding (gll linear)

    const int tid  = threadIdx.x;
    const int lane = tid & 63;
    const int w    = tid >> 6;           // 0..7
    const int blk  = blockIdx.x;         // 0..255
    const int skew = blk & 31;           // per-block K-phase
    const int m_base = blk * 64;
    const int fm = lane & 15;
    const int fq = lane >> 4;
    const int fk = fq * 8;
    const int fr = fq * 4;
    const int wm = w >> 2;               // row half: 0,1
    const int wn = w & 3;                // col group: 0..3

    // staging: wave w stages rows w*8..w*8+7; lane l -> row w*8+(l>>3),
    // physical 16B slot (l&7) receives logical slot (l&7)^(l>>3).
    const float* gsrc = &x[(size_t)(m_base + w * 8 + (lane >> 3)) * CC
                           + ((lane & 7) ^ (lane >> 3)) * 4];
    float* ldst = &xs[0][w * 8][0];      // + buf*2048 floats

    const _Float16* wb = &Wp[(wn * 48 + fm) * 32 + fk];

    floatx4 acc[2][3];
    #pragma unroll
    for (int a = 0; a < 2; ++a)
        #pragma unroll
        for (int n = 0; n < 3; ++n)
            #pragma unroll
            for (int r = 0; r < 4; ++r) acc[a][n][r] = 0.0f;

    half8 wA[3], wB[3];

    // ---- prologue: W(p(0)) -> wA; gll p(0),p(1),p(2) -> slots 0,1,2 ----
    #pragma unroll
    for (int n = 0; n < 3; ++n)
        wA[n] = *reinterpret_cast<const half8*>(wb + (size_t)skew * 6144 + n * 512);
    MEMFENCE;
    gll16(gsrc + (size_t)((skew + 0) & 31) * 32, ldst + 0 * 2048);
    gll16(gsrc + (size_t)((skew + 1) & 31) * 32, ldst + 1 * 2048);
    gll16(gsrc + (size_t)((skew + 2) & 31) * 32, ldst + 2 * 2048);
    asm volatile("s_waitcnt vmcnt(2)" ::: "memory");   // gll(p0)+W(p0) done
    __builtin_amdgcn_s_barrier();
    MEMFENCE;

    // One iter i: [issue W(p(i+1))] [issue gll(p(i+3))] [compute p(i)]
    //             [vmcnt(N)] [bar]
#define QKV_ITER(c, WUSE, WLOAD, DO_W, DO_X, NWAIT)                            \
    {                                                                          \
        if (DO_W) {                                                            \
            const int pw = ((c) + 1 + skew) & 31;                              \
            _Pragma("unroll")                                                  \
            for (int n = 0; n < 3; ++n)                                        \
                WLOAD[n] = *reinterpret_cast<const half8*>(                    \
                    wb + (size_t)pw * 6144 + n * 512);                         \
        }                                                                      \
        MEMFENCE;                                                              \
        if (DO_X) {                                                            \
            const int px = ((c) + 3 + skew) & 31;                              \
            gll16(gsrc + (size_t)px * 32, ldst + (((c) + 3) & 3) * 2048);      \
        }                                                                      \
        _Pragma("unroll")                                                      \
        for (int a = 0; a < 2; ++a) {                                          \
            const int rr = wm * 32 + a * 16 + fm;                              \
            const float* rowp = &xs[(c) & 3][rr][0];                           \
            const int sw = fm & 7;                                             \
            const float4 v0 = *reinterpret_cast<const float4*>(                \
                rowp + ((fq * 2 + 0) ^ sw) * 4);                               \
            const float4 v1 = *reinterpret_cast<const float4*>(                \
                rowp + ((fq * 2 + 1) ^ sw) * 4);                               \
            const half8 af = { (_Float16)v0.x, (_Float16)v0.y,                 \
                               (_Float16)v0.z, (_Float16)v0.w,                 \
                               (_Float16)v1.x, (_Float16)v1.y,                 \
                               (_Float16)v1.z, (_Float16)v1.w };               \
            _Pragma("unroll")                                                  \
            for (int n = 0; n < 3; ++n)                                        \
                acc[a][n] = __builtin_amdgcn_mfma_f32_16x16x32_f16(            \
                    af, WUSE[n], acc[a][n], 0, 0, 0);                          \
        }                                                                      \
        asm volatile("s_waitcnt vmcnt(" #NWAIT ")" ::: "memory");              \
        __builtin_amdgcn_s_barrier();                                          \
        MEMFENCE;                                                              \
    }

    for (int cc = 0; cc < 28; cc += 2) {
        QKV_ITER(cc,     wA, wB, true,  true,  8);
        QKV_ITER(cc + 1, wB, wA, true,  true,  8);
    }
    QKV_ITER(28, wA, wB, true,  true,  8);   // issues W(29), gll(31)
    QKV_ITER(29, wB, wA, true,  false, 4);   // issues W(30); gll(30) done
    QKV_ITER(30, wA, wB, true,  false, 0);   // issues W(31); gll(31) done
    QKV_ITER(31, wB, wA, false, false, 0);   // pure compute
#undef QKV_ITER

    // ---- epilogue: col = wn*48 + n*16 + fm, 16-row tile mt ----
    #pragma unroll
    for (int a = 0; a < 2; ++a) {
        const int mt = blk * 4 + wm * 2 + a;
        #pragma unroll
        for (int n = 0; n < 3; ++n) {
            const int col = wn * 48 + n * 16 + fm;
            if (col < 64) {                          // q: row-major
                #pragma unroll
                for (int r = 0; r < 4; ++r)
                    q16[(size_t)(mt * 16 + fr + r) * HH + col] = (_Float16)acc[a][n][r];
            } else if (col < 128) {                  // k: fragment-packed
                const int h = col - 64;
                _Float16* kp = &Kp[(size_t)(mt * 2 + (h >> 5)) * 512 + (h & 31)];
                #pragma unroll
                for (int r = 0; r < 4; ++r)
                    kp[(fr + r) * 32] = (_Float16)acc[a][n][r];
            } else {                                 // v: fragment-packed (transposed)
                const int h = col - 128;
                const half4 pk = { (_Float16)acc[a][n][0], (_Float16)acc[a][n][1],
                                   (_Float16)acc[a][n][2], (_Float16)acc[a][n][3] };
                *reinterpret_cast<half4*>(
                    &Vp[(size_t)((mt >> 2) * 4 + (h >> 4)) * 1024 +
                        ((mt >> 1) & 1) * 512 + fm * 32 + (mt & 1) * 16 + fr]) = pk;
            }
        }
    }
}

// ---------------------------------------------------------------------------
// Kernel 2: barrier-free split-K causal attention. 3072 single-wave blocks =
// 128 q-tiles(16 rows) x 8 batches x 3 key-segments, longest-first.
// 12 waves/CU (3/SIMD). K/V B-frags: contiguous 1 KB loads from Kp/Vp
// (L2-hot). P via 2.2 KB wave-private LDS (lgkmcnt ordering only).
// DPP row-max + ones-MFMA row-sum. Partials: seg0 -> out (fp32), segs 1,2 ->
// fp16 Op; (m,l) -> ml.
// ---------------------------------------------------------------------------
__global__ __launch_bounds__(64, 4)
void attn7(const _Float16* __restrict__ q16, const _Float16* __restrict__ Kp,
           const _Float16* __restrict__ Vp, float* __restrict__ out,
           _Float16* __restrict__ Op, float* __restrict__ ml)
{
    __shared__ _Float16 Ps[16 * 68];

    const int bid = blockIdx.x;           // 0..3071
    const int it  = 127 - bid / 24;       // longest q-tiles first
    const int sub = bid - (127 - it) * 24;
    const int b   = sub & 7;
    const int s   = sub >> 3;             // segment 0..2

    const int lane = threadIdx.x;
    const int fm = lane & 15;
    const int fq = lane >> 4;
    const int fk = fq * 8;
    const int fr = fq * 4;

    const int Ji = (it >> 2) + 1;
    const int qq = Ji / 3, rem = Ji - qq * 3;
    const int cnt   = qq + (s < rem ? 1 : 0);
    const int start = s * qq + (s < rem ? s : rem);

    const _Float16* __restrict__ kpb = Kp + (size_t)b * TT * HH;
    const _Float16* __restrict__ vpb = Vp + (size_t)b * TT * HH;

    const int qrow = (b * 128 + it) * 16 + fm;
    const half8 qf0 = *reinterpret_cast<const half8*>(&q16[(size_t)qrow * HH + fk]);
    const half8 qf1 = *reinterpret_cast<const half8*>(&q16[(size_t)qrow * HH + 32 + fk]);

    floatx4 O[4], lacc;
    float m_r[4];
    #pragma unroll
    for (int r = 0; r < 4; ++r) {
        m_r[r] = -3.0e38f;
        lacc[r] = 0.0f;
        #pragma unroll
        for (int ht = 0; ht < 4; ++ht) O[ht][r] = 0.0f;
    }
    const half8 ones = { (_Float16)1.f, (_Float16)1.f, (_Float16)1.f, (_Float16)1.f,
                         (_Float16)1.f, (_Float16)1.f, (_Float16)1.f, (_Float16)1.f };

    const int loff = fm * 32 + fk;        // per-lane offset inside a packed frag

    for (int js = 0; js < cnt; ++js) {
        const int jj = start + js;

        // ---- S = Q K^T : 8 MFMAs, B-frags = contiguous 1KB packed loads ----
        floatx4 sa[4];
        #pragma unroll
        for (int nt = 0; nt < 4; ++nt) {
            #pragma unroll
            for (int r = 0; r < 4; ++r) sa[nt][r] = 0.0f;
            const _Float16* kp = &kpb[(size_t)(jj * 4 + nt) * 1024];
            const half8 b0 = *reinterpret_cast<const half8*>(kp + loff);
            const half8 b1 = *reinterpret_cast<const half8*>(kp + 512 + loff);
            sa[nt] = __builtin_amdgcn_mfma_f32_16x16x32_f16(qf0, b0, sa[nt], 0, 0, 0);
            sa[nt] = __builtin_amdgcn_mfma_f32_16x16x32_f16(qf1, b1, sa[nt], 0, 0, 0);
        }

        // ---- causal mask (only the diagonal tile) ----
        if (jj == (it >> 2)) {
            const int rbase = it * 16 + fr;
            #pragma unroll
            for (int nt = 0; nt < 4; ++nt) {
                const int col = jj * 64 + nt * 16 + fm;
                #pragma unroll
                for (int r = 0; r < 4; ++r)
                    if (col > rbase + r) sa[nt][r] = -3.0e38f;
            }
        }

        // ---- online softmax: DPP row-max; row-sum via ones-MFMA ----
        #pragma unroll
        for (int r = 0; r < 4; ++r) {
            float mx = fmaxf(fmaxf(sa[0][r], sa[1][r]), fmaxf(sa[2][r], sa[3][r]));
            mx = rowmax16(mx);
            const float mn = fmaxf(m_r[r], mx);
            const float alpha = __expf(m_r[r] - mn);
            m_r[r] = mn;
            _Float16* pp = &Ps[(fr + r) * 68 + fm];
            pp[0]  = (_Float16)__expf(sa[0][r] - mn);
            pp[16] = (_Float16)__expf(sa[1][r] - mn);
            pp[32] = (_Float16)__expf(sa[2][r] - mn);
            pp[48] = (_Float16)__expf(sa[3][r] - mn);
            lacc[r] *= alpha;
            O[0][r] *= alpha; O[1][r] *= alpha; O[2][r] *= alpha; O[3][r] *= alpha;
        }
        // wave-private LDS: lgkmcnt ordering suffices, no barrier

        // ---- O += P V, l += P 1 : 10 MFMAs ----
        #pragma unroll
        for (int ch = 0; ch < 2; ++ch) {
            const half8 pa = *reinterpret_cast<const half8*>(&Ps[fm * 68 + ch * 32 + fk]);
            lacc = __builtin_amdgcn_mfma_f32_16x16x32_f16(pa, ones, lacc, 0, 0, 0);
            #pragma unroll
            for (int ht = 0; ht < 4; ++ht) {
                const half8 vb = *reinterpret_cast<const half8*>(
                    &vpb[(size_t)(jj * 4 + ht) * 1024 + ch * 512 + loff]);
                O[ht] = __builtin_amdgcn_mfma_f32_16x16x32_f16(pa, vb, O[ht], 0, 0, 0);
            }
        }
    }

    // ---- epilogue: write segment partial (unnormalized O, m, l) ----
    #pragma unroll
    for (int r = 0; r < 4; ++r) {
        const int grow = (b * 128 + it) * 16 + fr + r;
        if (s == 0) {
            #pragma unroll
            for (int ht = 0; ht < 4; ++ht)
                out[(size_t)grow * HH + ht * 16 + fm] = O[ht][r];
        } else {
            #pragma unroll
            for (int ht = 0; ht < 4; ++ht)
                Op[((size_t)(s - 1) * MM + grow) * HH + ht * 16 + fm] = (_Float16)O[ht][r];
        }
        if (fm == 0) {
            ml[((size_t)s * MM + grow) * 2 + 0] = m_r[r];
            ml[((size_t)s * MM + grow) * 2 + 1] = lacc[r];
        }
    }
}

// ---------------------------------------------------------------------------
// Kernel 3: flash-decode combine of the 3 segment partials.
// ---------------------------------------------------------------------------
__global__ __launch_bounds__(256)
void combine(float* __restrict__ out, const _Float16* __restrict__ Op,
             const float* __restrict__ ml)
{
    const int tid  = threadIdx.x;
    const int grow = blockIdx.x * 64 + (tid >> 2);
    const int c0   = (tid & 3) * 16;

    const float m0 = ml[(size_t)grow * 2 + 0];
    const float l0 = ml[(size_t)grow * 2 + 1];
    const float m1 = ml[((size_t)MM + grow) * 2 + 0];
    const float l1 = ml[((size_t)MM + grow) * 2 + 1];
    const float m2 = ml[((size_t)2 * MM + grow) * 2 + 0];
    const float l2 = ml[((size_t)2 * MM + grow) * 2 + 1];

    const float M  = fmaxf(m0, fmaxf(m1, m2));
    const float w0 = __expf(m0 - M);
    const float w1 = __expf(m1 - M);
    const float w2 = __expf(m2 - M);
    const float inv = 1.0f / (w0 * l0 + w1 * l1 + w2 * l2);

    #pragma unroll
    for (int i = 0; i < 16; i += 4) {
        float4 o0 = *reinterpret_cast<float4*>(&out[(size_t)grow * HH + c0 + i]);
        const half4 h1 = *reinterpret_cast<const half4*>(&Op[(size_t)grow * HH + c0 + i]);
        const half4 h2 = *reinterpret_cast<const half4*>(&Op[(size_t)MM * HH + (size_t)grow * HH + c0 + i]);
        o0.x = (w0 * o0.x + w1 * (float)h1[0] + w2 * (float)h2[0]) * inv;
        o0.y = (w0 * o0.y + w1 * (float)h1[1] + w2 * (float)h2[1]) * inv;
        o0.z = (w0 * o0.z + w1 * (float)h1[2] + w2 * (float)h2[2]) * inv;
        o0.w = (w0 * o0.w + w1 * (float)h1[3] + w2 * (float)h2[3]) * inv;
        *reinterpret_cast<float4*>(&out[(size_t)grow * HH + c0 + i]) = o0;
    }
}

// ---------------------------------------------------------------------------
extern "C" void kernel_launch(void* const* d_in, const int* in_sizes, int n_in,
                              void* d_out, int out_size, void* d_ws, size_t ws_size,
                              hipStream_t stream)
{
    (void)in_sizes; (void)n_in; (void)out_size; (void)ws_size;

    const float* x  = (const float*)d_in[0];
    const float* Wk = (const float*)d_in[1];
    const float* Wq = (const float*)d_in[2];
    const float* Wv = (const float*)d_in[3];
    float* out = (float*)d_out;

    _Float16* base = (_Float16*)d_ws;
    _Float16* q16 = base;                                  // MM*HH halves
    _Float16* Kp  = base + (size_t)MM * HH;                // MM*HH
    _Float16* Vp  = base + (size_t)2 * MM * HH;            // MM*HH
    _Float16* Wp  = base + (size_t)3 * MM * HH;            // 192*1024
    _Float16* Op  = Wp + 192 * 1024;                       // 2*MM*HH
    float*    ml  = (float*)(Op + (size_t)2 * MM * HH);    // 3*MM*2 floats

    w_pack<<<dim3(96), dim3(256), 0, stream>>>(Wk, Wq, Wv, Wp);
    qkv10<<<dim3(256), dim3(512), 0, stream>>>(x, Wp, q16, Kp, Vp);
    attn7<<<dim3(3072), dim3(64), 0, stream>>>(q16, Kp, Vp, out, Op, ml);
    combine<<<dim3(256), dim3(256), 0, stream>>>(out, Op, ml);
}